// Round 5
// baseline (949.603 us; speedup 1.0000x reference)
//
#include <hip/hip_runtime.h>

typedef unsigned short u16;
typedef __attribute__((ext_vector_type(8))) __bf16 bf16x8;
typedef __attribute__((ext_vector_type(4))) float f32x4;

// ---------- bf16 helpers (OCP bf16 = high 16 bits of fp32, RNE) ----------
__device__ __forceinline__ float b2f(u16 u) {
    unsigned int i = ((unsigned int)u) << 16;
    return __builtin_bit_cast(float, i);
}
__device__ __forceinline__ u16 f2b(float f) {
    unsigned int x = __builtin_bit_cast(unsigned int, f);
    x += 0x7fffu + ((x >> 16) & 1u);
    return (u16)(x >> 16);
}
__device__ __forceinline__ void gld_lds16(const void* g, void* l) {
    __builtin_amdgcn_global_load_lds(
        (const __attribute__((address_space(1))) unsigned int*)g,
        (__attribute__((address_space(3))) unsigned int*)l, 16, 0, 0);
}

// ---------- XCD-chunked + 4x4-supertile tile remap ----------
// HW round-robins consecutive flat block ids across the 8 XCD L2s. Remap so
// each XCD owns a contiguous chunk of tile space, traversed in 4x4 supertiles:
// per-supertile working set = 4 A-panels + 4 W-panels = 4MB = one XCD L2.
// Bijective iff total%8==0, gx%4==0, gy%4==0 (all our grids qualify).
__device__ __forceinline__ void tile_swz(int& tx, int& ty, int& tz)
{
    const int gx = gridDim.x, gy = gridDim.y;
    const int nb = gx * gy;
    const int total = nb * gridDim.z;
    const int flat = blockIdx.x + gx * (blockIdx.y + gy * blockIdx.z);
    const int q = total >> 3;
    const int t = (flat & 7) * q + (flat >> 3);
    tz = t / nb;
    const int r = t - tz * nb;
    const int ncs = gx >> 2;          // supertile columns
    const int st = r >> 4, w2 = r & 15;
    tx = (st % ncs) * 4 + (w2 & 3);
    ty = (st / ncs) * 4 + (w2 >> 2);
}

// ---------- batched f32 -> bf16 weight conversion (z-fused up to 3) ----------
struct CVT3 { const float* s0; u16* d0; const float* s1; u16* d1;
              const float* s2; u16* d2; };
__global__ __launch_bounds__(256) void cvt3_f32_bf16(CVT3 c, int n4)
{
    const float* s = (blockIdx.z == 0) ? c.s0 : ((blockIdx.z == 1) ? c.s1 : c.s2);
    u16* d = (blockIdx.z == 0) ? c.d0 : ((blockIdx.z == 1) ? c.d1 : c.d2);
    int i = blockIdx.x * 256 + threadIdx.x;
    if (i < n4) {
        float4 v = ((const float4*)s)[i];
        ushort4 o;
        o.x = f2b(v.x); o.y = f2b(v.y); o.z = f2b(v.z); o.w = f2b(v.w);
        ((ushort4*)d)[i] = o;
    }
}

// ---------- reduce 3 partials into io (f32, element-wise) ----------
__global__ __launch_bounds__(256) void reduce3_into(
    const float* __restrict__ p0, const float* __restrict__ p1,
    const float* __restrict__ p2, float* __restrict__ io, int n4)
{
    int i = blockIdx.x * 256 + threadIdx.x;
    if (i < n4) {
        float4 a = ((const float4*)p0)[i];
        float4 b = ((const float4*)p1)[i];
        float4 c = ((const float4*)p2)[i];
        float4 d = ((float4*)io)[i];
        d.x += a.x + b.x + c.x; d.y += a.y + b.y + c.y;
        d.z += a.z + b.z + c.z; d.w += a.w + b.w + c.w;
        ((float4*)io)[i] = d;
    }
}

// ---------- epilogue modes ----------
enum { EP_BF16 = 0, EP_BF16_BIAS, EP_BF16_RELU, EP_BF16_KV, EP_BF16_BIAS_VT, EP_F32_OUT };

// C[M,N] = A[M,K] @ W[N,K]^T   (both bf16 row-major, K contiguous)
// m97-style: 128x128 tile, BK=64, 4 waves, 4x4 of 16x16x32 MFMA, global_load_lds w=16
template <int MODE>
__global__ __launch_bounds__(256) void gemm_bt(
    const u16* __restrict__ A, const u16* __restrict__ W,
    const float* __restrict__ bias, void* __restrict__ out,
    int M, int N, int K)
{
    __shared__ u16 As[128 * 64];
    __shared__ u16 Bs[128 * 64];
    int tx, ty, tz;
    tile_swz(tx, ty, tz);
    const int tid = threadIdx.x;
    const int row0 = ty * 128, col0 = tx * 128;
    const int wave = tid >> 6, lane = tid & 63, quad = lane >> 4, l16 = lane & 15;
    const int wm = (wave >> 1) * 64, wn = (wave & 1) * 64;

    f32x4 acc[4][4];
#pragma unroll
    for (int i = 0; i < 4; ++i)
#pragma unroll
        for (int j = 0; j < 4; ++j) acc[i][j] = (f32x4){0.f, 0.f, 0.f, 0.f};

    const char* Ab = (const char*)A + (size_t)row0 * K * 2;
    const char* Wb = (const char*)W + (size_t)col0 * K * 2;
    const size_t ldb = (size_t)K * 2;

    for (int k0 = 0; k0 < K; k0 += 64) {
#pragma unroll
        for (int r = 0; r < 4; ++r) {
            int o = r * 4096 + tid * 16;
            int trow = o >> 7, tcolb = o & 127;
            gld_lds16(Ab + (size_t)trow * ldb + (size_t)k0 * 2 + tcolb, (char*)As + o);
            gld_lds16(Wb + (size_t)trow * ldb + (size_t)k0 * 2 + tcolb, (char*)Bs + o);
        }
        __syncthreads();
#pragma unroll
        for (int ks = 0; ks < 2; ++ks) {
            bf16x8 af[4], bfr[4];
#pragma unroll
            for (int i = 0; i < 4; ++i)
                af[i] = *(const bf16x8*)(As + (wm + i * 16 + l16) * 64 + ks * 32 + quad * 8);
#pragma unroll
            for (int j = 0; j < 4; ++j)
                bfr[j] = *(const bf16x8*)(Bs + (wn + j * 16 + l16) * 64 + ks * 32 + quad * 8);
#pragma unroll
            for (int i = 0; i < 4; ++i)
#pragma unroll
                for (int j = 0; j < 4; ++j)
                    acc[i][j] = __builtin_amdgcn_mfma_f32_16x16x32_bf16(af[i], bfr[j], acc[i][j], 0, 0, 0);
        }
        __syncthreads();
    }

    // epilogue: C[row=quad*4+reg][col=l16] per 16x16 tile (verified m89/m91 layout)
#pragma unroll
    for (int j = 0; j < 4; ++j) {
        int gcol = col0 + wn + j * 16 + l16;
        float bv = 0.f;
        if (MODE == EP_BF16_BIAS || MODE == EP_BF16_BIAS_VT) bv = bias[gcol];
#pragma unroll
        for (int i = 0; i < 4; ++i) {
            int growb = row0 + wm + i * 16 + quad * 4;
#pragma unroll
            for (int reg = 0; reg < 4; ++reg) {
                int grow = growb + reg;
                float v = acc[i][j][reg] + bv;
                if (MODE == EP_BF16_RELU) v = fmaxf(v, 0.f);
                if (MODE == EP_F32_OUT) {
                    ((float*)out)[(size_t)grow * N + gcol] = v;
                } else if (MODE == EP_BF16_KV) {
                    int b = grow >> 10, s = grow & 1023;
                    ((u16*)out)[((size_t)(b * 1536 + 512 + s)) * N + gcol] = f2b(v);
                } else if (MODE == EP_BF16_BIAS_VT) {
                    int b = (grow >= 1536) ? 1 : 0;
                    int jk = grow - b * 1536;
                    ((u16*)out)[((size_t)(b * 2048 + gcol)) * 1536 + jk] = f2b(v);
                } else {
                    ((u16*)out)[(size_t)grow * N + gcol] = f2b(v);
                }
            }
        }
    }
}

// ---------- z-fused GEMM: logical z selects an independent (A,W,bias,out,M,mode) ----------
struct FuseA { const u16* A; const u16* W; const float* bias; void* out; int M; int mode; };
struct Fuse3 { FuseA z0, z1, z2; };

__global__ __launch_bounds__(256) void gemm_bt_f(Fuse3 f, int K)
{
    int tx, ty, tz;
    tile_swz(tx, ty, tz);
    FuseA p = (tz == 0) ? f.z0 : ((tz == 1) ? f.z1 : f.z2);
    const int row0 = ty * 128, col0 = tx * 128;
    if (row0 >= p.M) return;   // uniform per block: safe before barriers

    __shared__ u16 As[128 * 64];
    __shared__ u16 Bs[128 * 64];
    const int tid = threadIdx.x;
    const int wave = tid >> 6, lane = tid & 63, quad = lane >> 4, l16 = lane & 15;
    const int wm = (wave >> 1) * 64, wn = (wave & 1) * 64;

    f32x4 acc[4][4];
#pragma unroll
    for (int i = 0; i < 4; ++i)
#pragma unroll
        for (int j = 0; j < 4; ++j) acc[i][j] = (f32x4){0.f, 0.f, 0.f, 0.f};

    const char* Ab = (const char*)p.A + (size_t)row0 * K * 2;
    const char* Wb = (const char*)p.W + (size_t)col0 * K * 2;
    const size_t ldb = (size_t)K * 2;

    for (int k0 = 0; k0 < K; k0 += 64) {
#pragma unroll
        for (int r = 0; r < 4; ++r) {
            int o = r * 4096 + tid * 16;
            int trow = o >> 7, tcolb = o & 127;
            gld_lds16(Ab + (size_t)trow * ldb + (size_t)k0 * 2 + tcolb, (char*)As + o);
            gld_lds16(Wb + (size_t)trow * ldb + (size_t)k0 * 2 + tcolb, (char*)Bs + o);
        }
        __syncthreads();
#pragma unroll
        for (int ks = 0; ks < 2; ++ks) {
            bf16x8 af[4], bfr[4];
#pragma unroll
            for (int i = 0; i < 4; ++i)
                af[i] = *(const bf16x8*)(As + (wm + i * 16 + l16) * 64 + ks * 32 + quad * 8);
#pragma unroll
            for (int j = 0; j < 4; ++j)
                bfr[j] = *(const bf16x8*)(Bs + (wn + j * 16 + l16) * 64 + ks * 32 + quad * 8);
#pragma unroll
            for (int i = 0; i < 4; ++i)
#pragma unroll
                for (int j = 0; j < 4; ++j)
                    acc[i][j] = __builtin_amdgcn_mfma_f32_16x16x32_bf16(af[i], bfr[j], acc[i][j], 0, 0, 0);
        }
        __syncthreads();
    }

#pragma unroll
    for (int j = 0; j < 4; ++j) {
        int gcol = col0 + wn + j * 16 + l16;
        float bv = (p.mode == EP_BF16_BIAS || p.mode == EP_BF16_BIAS_VT) ? p.bias[gcol] : 0.f;
#pragma unroll
        for (int i = 0; i < 4; ++i) {
            int growb = row0 + wm + i * 16 + quad * 4;
#pragma unroll
            for (int reg = 0; reg < 4; ++reg) {
                int grow = growb + reg;
                u16 hv = f2b(acc[i][j][reg] + bv);
                size_t idx;
                if (p.mode == EP_BF16_KV) {
                    int b = grow >> 10, s = grow & 1023;
                    idx = ((size_t)(b * 1536 + 512 + s)) * 2048 + gcol;
                } else if (p.mode == EP_BF16_BIAS_VT) {
                    int b = (grow >= 1536) ? 1 : 0;
                    int jk = grow - b * 1536;
                    idx = ((size_t)(b * 2048 + gcol)) * 1536 + jk;
                } else {
                    idx = (size_t)grow * 2048 + gcol;
                }
                ((u16*)p.out)[idx] = hv;
            }
        }
    }
}

// ---------- split-K GEMM into per-slice f32 partial buffers (no atomics) ----------
// logical z picks K-chunk [z*Kc, (z+1)*Kc) and output buffer o[z].
// bias (if non-null) added by slice 0 only.
struct SKP { const u16* A; const u16* W; const float* bias;
             float* o0; float* o1; float* o2; float* o3; int N, K, Kc; };

__global__ __launch_bounds__(256) void gemm_bt_p(SKP s)
{
    __shared__ u16 As[128 * 64];
    __shared__ u16 Bs[128 * 64];
    int tx, ty, tz;
    tile_swz(tx, ty, tz);
    const int tid = threadIdx.x;
    const int row0 = ty * 128, col0 = tx * 128;
    const int wave = tid >> 6, lane = tid & 63, quad = lane >> 4, l16 = lane & 15;
    const int wm = (wave >> 1) * 64, wn = (wave & 1) * 64;
    float* out = (tz == 0) ? s.o0 : ((tz == 1) ? s.o1 : ((tz == 2) ? s.o2 : s.o3));
    const int kbeg = tz * s.Kc, kend = kbeg + s.Kc;

    f32x4 acc[4][4];
#pragma unroll
    for (int i = 0; i < 4; ++i)
#pragma unroll
        for (int j = 0; j < 4; ++j) acc[i][j] = (f32x4){0.f, 0.f, 0.f, 0.f};

    const char* Ab = (const char*)s.A + (size_t)row0 * s.K * 2;
    const char* Wb = (const char*)s.W + (size_t)col0 * s.K * 2;
    const size_t ldb = (size_t)s.K * 2;

    for (int k0 = kbeg; k0 < kend; k0 += 64) {
#pragma unroll
        for (int r = 0; r < 4; ++r) {
            int o = r * 4096 + tid * 16;
            int trow = o >> 7, tcolb = o & 127;
            gld_lds16(Ab + (size_t)trow * ldb + (size_t)k0 * 2 + tcolb, (char*)As + o);
            gld_lds16(Wb + (size_t)trow * ldb + (size_t)k0 * 2 + tcolb, (char*)Bs + o);
        }
        __syncthreads();
#pragma unroll
        for (int ks = 0; ks < 2; ++ks) {
            bf16x8 af[4], bfr[4];
#pragma unroll
            for (int i = 0; i < 4; ++i)
                af[i] = *(const bf16x8*)(As + (wm + i * 16 + l16) * 64 + ks * 32 + quad * 8);
#pragma unroll
            for (int j = 0; j < 4; ++j)
                bfr[j] = *(const bf16x8*)(Bs + (wn + j * 16 + l16) * 64 + ks * 32 + quad * 8);
#pragma unroll
            for (int i = 0; i < 4; ++i)
#pragma unroll
                for (int j = 0; j < 4; ++j)
                    acc[i][j] = __builtin_amdgcn_mfma_f32_16x16x32_bf16(af[i], bfr[j], acc[i][j], 0, 0, 0);
        }
        __syncthreads();
    }

#pragma unroll
    for (int j = 0; j < 4; ++j) {
        int gcol = col0 + wn + j * 16 + l16;
        float bv = (s.bias != nullptr && tz == 0) ? s.bias[gcol] : 0.f;
#pragma unroll
        for (int i = 0; i < 4; ++i) {
            int growb = row0 + wm + i * 16 + quad * 4;
#pragma unroll
            for (int reg = 0; reg < 4; ++reg) {
                int grow = growb + reg;
                out[(size_t)grow * s.N + gcol] = acc[i][j][reg] + bv;
            }
        }
    }
}

// ---------- LayerNorm over rows of 2048 (input fp32 or bf16, output bf16) ----------
template <int IN_F32>
__global__ __launch_bounds__(256) void ln_rows(
    const void* __restrict__ in, const float* __restrict__ gamma,
    u16* __restrict__ out)
{
    const int row = blockIdx.x, tid = threadIdx.x;
    const float* inf = (const float*)in + (size_t)row * 2048;
    const u16* inb = (const u16*)in + (size_t)row * 2048;
    float v[8], s1 = 0.f, s2 = 0.f;
#pragma unroll
    for (int i = 0; i < 8; ++i) {
        int c = tid + i * 256;
        float x = IN_F32 ? inf[c] : b2f(inb[c]);
        v[i] = x; s1 += x; s2 += x * x;
    }
#pragma unroll
    for (int off = 32; off >= 1; off >>= 1) { s1 += __shfl_xor(s1, off, 64); s2 += __shfl_xor(s2, off, 64); }
    __shared__ float ra[4], rb[4];
    int wave = tid >> 6, lane = tid & 63;
    if (lane == 0) { ra[wave] = s1; rb[wave] = s2; }
    __syncthreads();
    s1 = ra[0] + ra[1] + ra[2] + ra[3];
    s2 = rb[0] + rb[1] + rb[2] + rb[3];
    float mean = s1 * (1.f / 2048.f);
    float var = s2 * (1.f / 2048.f) - mean * mean;
    float rstd = rsqrtf(var + 1e-5f);
#pragma unroll
    for (int i = 0; i < 8; ++i) {
        int c = tid + i * 256;
        out[(size_t)row * 2048 + c] = f2b((v[i] - mean) * rstd * gamma[c]);
    }
}

// ---------- reduce 4 f32 partials + LayerNorm -> bf16 ----------
__global__ __launch_bounds__(256) void ln4_rows(
    const float* __restrict__ p0, const float* __restrict__ p1,
    const float* __restrict__ p2, const float* __restrict__ p3,
    const float* __restrict__ gamma, u16* __restrict__ out)
{
    const int row = blockIdx.x, tid = threadIdx.x;
    const size_t rb_ = (size_t)row * 2048;
    float v[8], s1 = 0.f, s2 = 0.f;
#pragma unroll
    for (int i = 0; i < 8; ++i) {
        int c = tid + i * 256;
        float x = p0[rb_ + c] + p1[rb_ + c] + p2[rb_ + c] + p3[rb_ + c];
        v[i] = x; s1 += x; s2 += x * x;
    }
#pragma unroll
    for (int off = 32; off >= 1; off >>= 1) { s1 += __shfl_xor(s1, off, 64); s2 += __shfl_xor(s2, off, 64); }
    __shared__ float ra[4], rbs[4];
    int wave = tid >> 6, lane = tid & 63;
    if (lane == 0) { ra[wave] = s1; rbs[wave] = s2; }
    __syncthreads();
    s1 = ra[0] + ra[1] + ra[2] + ra[3];
    s2 = rbs[0] + rbs[1] + rbs[2] + rbs[3];
    float mean = s1 * (1.f / 2048.f);
    float rstd = rsqrtf(s2 * (1.f / 2048.f) - mean * mean + 1e-5f);
#pragma unroll
    for (int i = 0; i < 8; ++i) {
        int c = tid + i * 256;
        out[rb_ + c] = f2b((v[i] - mean) * rstd * gamma[c]);
    }
}

// ---------- LN + RoPE for new q,k rows (bf16 pre-activations in ws) ----------
__global__ __launch_bounds__(256) void qk_post(
    const u16* __restrict__ qpre, const u16* __restrict__ kpre,
    const float* __restrict__ gq, const float* __restrict__ gk,
    const float* __restrict__ rotary, const float* __restrict__ xscale,
    u16* __restrict__ qrope, u16* __restrict__ kfull)
{
    const int is_k = blockIdx.x & 1;
    const int row = blockIdx.x >> 1;           // b*1024 + s
    const int b = row >> 10, s = row & 1023;
    const int tid = threadIdx.x, base = tid * 8;
    const u16* in = (is_k ? kpre : qpre) + (size_t)row * 2048;
    float v[8], s1 = 0.f, s2 = 0.f;
#pragma unroll
    for (int i = 0; i < 8; ++i) { float x = b2f(in[base + i]); v[i] = x; s1 += x; s2 += x * x; }
#pragma unroll
    for (int off = 32; off >= 1; off >>= 1) { s1 += __shfl_xor(s1, off, 64); s2 += __shfl_xor(s2, off, 64); }
    __shared__ float ra[4], rb[4];
    int wave = tid >> 6, lane = tid & 63;
    if (lane == 0) { ra[wave] = s1; rb[wave] = s2; }
    __syncthreads();
    s1 = ra[0] + ra[1] + ra[2] + ra[3];
    s2 = rb[0] + rb[1] + rb[2] + rb[3];
    float mean = s1 * (1.f / 2048.f);
    float rstd = rsqrtf(s2 * (1.f / 2048.f) - mean * mean + 1e-5f);
    const float* g = is_k ? gk : gq;
    const int rr = 512 + s;                    // rotary/xscale row
    u16* outp = is_k ? (kfull + ((size_t)(b * 1536 + 512 + s)) * 2048)
                     : (qrope + (size_t)row * 2048);
#pragma unroll
    for (int p = 0; p < 4; ++p) {
        int e0 = base + 2 * p, e1 = e0 + 1;
        float x0 = (v[2 * p] - mean) * rstd * g[e0];
        float x1 = (v[2 * p + 1] - mean) * rstd * g[e1];
        float f = rotary[(size_t)rr * 2048 + e0];
        float sn, cs; sincosf(f, &sn, &cs);
        float sc0 = xscale[(size_t)rr * 2048 + e0];
        float sc1 = xscale[(size_t)rr * 2048 + e1];
        if (is_k) { sc0 = 1.f / sc0; sc1 = 1.f / sc1; }
        outp[e0] = f2b((x0 * cs - x1 * sn) * sc0);
        outp[e1] = f2b((x1 * cs + x0 * sn) * sc1);
    }
}

// ---------- cache rows: rope(cache_k) -> k_full[0..511], cvt cache_v -> v_full ----------
__global__ __launch_bounds__(256) void cache_prep(
    const float* __restrict__ cache_k, const float* __restrict__ cache_v,
    const float* __restrict__ rotary, const float* __restrict__ xscale,
    u16* __restrict__ kfull, u16* __restrict__ vfull)
{
    const int row = blockIdx.x;                // b*512 + j
    const int b = row >> 9, j = row & 511;
    const int base = threadIdx.x * 8;
    const float* ck = cache_k + ((size_t)row) * 2048;
    const float* cv = cache_v + ((size_t)row) * 2048;
    u16* ko = kfull + ((size_t)(b * 1536 + j)) * 2048;
    u16* vo = vfull + ((size_t)(b * 1536 + j)) * 2048;
#pragma unroll
    for (int p = 0; p < 4; ++p) {
        int e0 = base + 2 * p, e1 = e0 + 1;
        float x0 = ck[e0], x1 = ck[e1];
        float f = rotary[(size_t)j * 2048 + e0];
        float sn, cs; sincosf(f, &sn, &cs);
        float sc0 = 1.f / xscale[(size_t)j * 2048 + e0];
        float sc1 = 1.f / xscale[(size_t)j * 2048 + e1];
        ko[e0] = f2b((x0 * cs - x1 * sn) * sc0);
        ko[e1] = f2b((x1 * cs + x0 * sn) * sc1);
        vo[e0] = f2b(cv[e0]); vo[e1] = f2b(cv[e1]);
    }
}

// ---------- banded attention: each query attends to exactly keys (i, i+512] ----------
__global__ __launch_bounds__(256) void attn(
    const u16* __restrict__ qh, const u16* __restrict__ kh,
    const u16* __restrict__ vt, u16* __restrict__ o)
{
    __shared__ u16 Qs[16 * 128];
    __shared__ float Ss[16 * 544];
    __shared__ u16 Ps[16 * 544];
    __shared__ float Ls[16];
    const int qt = blockIdx.x, h = blockIdx.y, b = blockIdx.z;
    const int i0 = qt * 16;
    const int tid = threadIdx.x;
    const int wave = tid >> 6, lane = tid & 63, quad = lane >> 4, l16 = lane & 15;

    { // load 16x128 Q tile (one 16B chunk per thread)
        int r = tid >> 4, seg = tid & 15;
        const u16* src = qh + ((size_t)(b * 1024 + i0 + r)) * 2048 + h * 128 + seg * 8;
        *(uint4*)(Qs + r * 128 + seg * 8) = *(const uint4*)src;
    }
    __syncthreads();

    const float sm = 0.08838834764831845f;  // 1/sqrt(128)
    for (int kt = wave; kt < 33; kt += 4) {
        int jb = i0 + kt * 16;
        const u16* krow = kh + ((size_t)(b * 1536 + jb + l16)) * 2048 + h * 128 + quad * 8;
        const u16* qrow = Qs + l16 * 128 + quad * 8;
        f32x4 sacc = (f32x4){0.f, 0.f, 0.f, 0.f};
#pragma unroll
        for (int st = 0; st < 4; ++st) {
            bf16x8 aq = *(const bf16x8*)(qrow + st * 32);
            bf16x8 bk = *(const bf16x8*)(krow + st * 32);
            sacc = __builtin_amdgcn_mfma_f32_16x16x32_bf16(aq, bk, sacc, 0, 0, 0);
        }
        int jj = jb + l16;
#pragma unroll
        for (int reg = 0; reg < 4; ++reg) {
            int qi = i0 + quad * 4 + reg;
            bool valid = (jj > qi) && (jj <= qi + 512);
            Ss[(quad * 4 + reg) * 544 + kt * 16 + l16] = valid ? sacc[reg] * sm : -1e9f;
        }
    }
    __syncthreads();

    { // softmax: 16 threads per query row
        int g = tid >> 4, l = tid & 15;
        float m = -1e30f;
        for (int j = l; j < 528; j += 16) m = fmaxf(m, Ss[g * 544 + j]);
#pragma unroll
        for (int off = 8; off >= 1; off >>= 1) m = fmaxf(m, __shfl_xor(m, off, 16));
        float sum = 0.f;
        for (int j = l; j < 528; j += 16) {
            float e = __expf(Ss[g * 544 + j] - m);
            sum += e;
            Ps[g * 544 + j] = f2b(e);
        }
        Ps[g * 544 + 528 + l] = 0;   // pad keys 528..543
#pragma unroll
        for (int off = 8; off >= 1; off >>= 1) sum += __shfl_xor(sum, off, 16);
        if (l == 0) Ls[g] = sum;
    }
    __syncthreads();

    // O = P @ V via MFMA; V read transposed (contiguous in key)
    f32x4 oa0 = (f32x4){0.f, 0.f, 0.f, 0.f}, oa1 = oa0;
    const u16* vbase = vt + ((size_t)(b * 2048 + h * 128 + wave * 32 + l16)) * 1536 + i0;
    for (int jc = 0; jc < 17; ++jc) {
        bf16x8 pf = *(const bf16x8*)(Ps + l16 * 544 + jc * 32 + quad * 8);
        bf16x8 v0 = *(const bf16x8*)(vbase + jc * 32 + quad * 8);
        bf16x8 v1 = *(const bf16x8*)(vbase + (size_t)16 * 1536 + jc * 32 + quad * 8);
        oa0 = __builtin_amdgcn_mfma_f32_16x16x32_bf16(pf, v0, oa0, 0, 0, 0);
        oa1 = __builtin_amdgcn_mfma_f32_16x16x32_bf16(pf, v1, oa1, 0, 0, 0);
    }
#pragma unroll
    for (int reg = 0; reg < 4; ++reg) {
        int q = quad * 4 + reg;
        float inv = 1.f / Ls[q];
        size_t orow = ((size_t)(b * 1024 + i0 + q)) * 2048 + h * 128 + wave * 32;
        o[orow + l16] = f2b(oa0[reg] * inv);
        o[orow + 16 + l16] = f2b(oa1[reg] * inv);
    }
}

// ---------- launch ----------
extern "C" void kernel_launch(void* const* d_in, const int* in_sizes, int n_in,
                              void* d_out, int out_size, void* d_ws, size_t ws_size,
                              hipStream_t stream)
{
    const float* x       = (const float*)d_in[0];
    const float* cache_k = (const float*)d_in[1];
    const float* cache_v = (const float*)d_in[2];
    const float* rotary  = (const float*)d_in[3];
    const float* xscale  = (const float*)d_in[4];
    // d_in[5] mask: band computed analytically
    const float* g_in = (const float*)d_in[6];
    const float* Wq   = (const float*)d_in[7];
    const float* Wk   = (const float*)d_in[8];
    const float* Wv   = (const float*)d_in[9];
    const float* g_q  = (const float*)d_in[10];
    const float* g_k  = (const float*)d_in[11];
    const float* Wlq  = (const float*)d_in[12];
    const float* blq  = (const float*)d_in[13];
    const float* Wlk  = (const float*)d_in[14];
    const float* blk  = (const float*)d_in[15];
    const float* Wlv  = (const float*)d_in[16];
    const float* blv  = (const float*)d_in[17];
    const float* Wo   = (const float*)d_in[18];
    const float* bo   = (const float*)d_in[19];
    const float* g_ffn= (const float*)d_in[20];
    const float* W1   = (const float*)d_in[21];
    const float* W2   = (const float*)d_in[22];

    char* ws = (char*)d_ws;
    // slot map (bytes) — time-multiplexed, high-water 117.5MB (validated):
    // [0,8.39M)        xn -> obuf; late: w1_b/w2_b head
    // [8.39,16.78)     qpre(=qhb); late: WP3 head / w1_b/w2_b
    // [16.78,25.17)    kpre; late: WP3 tail / w1_b/w2_b
    // [25.17,37.75)    wq_b [25.17,33.55) -> khb -> wo_b [25.17,33.55) -> w1_b/w2_b tail
    // [33.55,50.33)    (in khb/vfull early) late: WP0 -> FP0
    // [37.75,50.33)    vfull
    // [50.33,62.91)    wv_b [50.33,58.72) -> kfull; late: WP1 -> FP1
    // [62.91,75.56)    wk_b [62.91,71.30) -> vt; late: FP2 head
    // [75.56,83.95)    qrope -> h1 (ln4 out)
    // [83.95,117.5)    wlq/wlk/wlv -> WP2 [83.95,100.73) -> h2 [83.95,117.5)
    u16* xn     = (u16*)(ws + 0);
    u16* qpre   = (u16*)(ws + 8388608);
    u16* kpre   = (u16*)(ws + 16777216);
    u16* wq_b   = (u16*)(ws + 25165824);
    u16* khb    = (u16*)(ws + 25165824);
    u16* vfull  = (u16*)(ws + 37748736);
    u16* wv_b   = (u16*)(ws + 50331648);
    u16* kfull  = (u16*)(ws + 50331648);
    u16* wk_b   = (u16*)(ws + 62914560);
    u16* vt     = (u16*)(ws + 62914560);
    u16* qrope  = (u16*)(ws + 75563008);
    u16* wlq_b  = (u16*)(ws + 83951616);
    u16* wlk_b  = (u16*)(ws + 92340224);
    u16* wlv_b  = (u16*)(ws + 100728832);
    u16* h2     = (u16*)(ws + 83951616);
    u16* qhb    = qpre;
    u16* obuf   = xn;
    u16* h1     = qrope;                      // over dead qrope
    u16* wo_b   = (u16*)(ws + 25165824);
    u16* w1_b   = (u16*)(ws + 0);             // 33.55MB [0,33.55)
    u16* w2_b   = (u16*)(ws + 0);
    // Wo partials (4 x 16.78MB f32), live Wo-GEMM..ln4:
    float* WP0  = (float*)(ws + 33554432);
    float* WP1  = (float*)(ws + 50331648);
    float* WP2  = (float*)(ws + 83951616);
    float* WP3  = (float*)(ws + 8388608);
    // FFN2 partials (3 x 16.78MB f32 + d_out), live FFN2..reduce:
    float* FP0  = (float*)(ws + 33554432);
    float* FP1  = (float*)(ws + 50331648);
    float* FP2  = (float*)(ws + 67108864);

    const int N1M = 4194304 / 4;    // 2048*2048 /4 (float4 count)
    const int N4M = 16777216 / 4;   // 8192*2048 /4

    ln_rows<1><<<2048, 256, 0, stream>>>(x, g_in, xn);
    cvt3_f32_bf16<<<dim3(N1M / 256, 1, 3), 256, 0, stream>>>(
        CVT3{Wq, wq_b, Wk, wk_b, Wv, wv_b}, N1M);

    // fused QKV: 768 blocks, XCD-chunked supertile swizzle
    Fuse3 fq;
    fq.z0 = FuseA{xn, wq_b, nullptr, (void*)qpre,  2048, EP_BF16};
    fq.z1 = FuseA{xn, wk_b, nullptr, (void*)kpre,  2048, EP_BF16};
    fq.z2 = FuseA{xn, wv_b, nullptr, (void*)vfull, 2048, EP_BF16_KV};
    gemm_bt_f<<<dim3(16, 16, 3), 256, 0, stream>>>(fq, 2048);

    cache_prep<<<1024, 256, 0, stream>>>(cache_k, cache_v, rotary, xscale, kfull, vfull);
    qk_post<<<4096, 256, 0, stream>>>(qpre, kpre, g_q, g_k, rotary, xscale, qrope, kfull);
    cvt3_f32_bf16<<<dim3(N1M / 256, 1, 3), 256, 0, stream>>>(
        CVT3{Wlq, wlq_b, Wlk, wlk_b, Wlv, wlv_b}, N1M);

    // fused linear projections: 1152 blocks (1024 active)
    Fuse3 fl;
    fl.z0 = FuseA{qrope, wlq_b, blq, (void*)qhb, 2048, EP_BF16_BIAS};
    fl.z1 = FuseA{kfull, wlk_b, blk, (void*)khb, 3072, EP_BF16_BIAS};
    fl.z2 = FuseA{vfull, wlv_b, blv, (void*)vt,  3072, EP_BF16_BIAS_VT};
    gemm_bt_f<<<dim3(16, 24, 3), 256, 0, stream>>>(fl, 2048);

    attn<<<dim3(64, 16, 2), 256, 0, stream>>>(qhb, khb, vt, obuf);

    // Wo: split-K x4 (Kc=512, 1024 blocks) into f32 partials, no atomics
    cvt3_f32_bf16<<<dim3(N1M / 256, 1, 1), 256, 0, stream>>>(
        CVT3{Wo, wo_b, Wo, wo_b, Wo, wo_b}, N1M);
    gemm_bt_p<<<dim3(16, 16, 4), 256, 0, stream>>>(
        SKP{obuf, wo_b, bo, WP0, WP1, WP2, WP3, 2048, 2048, 512});
    ln4_rows<<<2048, 256, 0, stream>>>(WP0, WP1, WP2, WP3, g_ffn, h1);

    // FFN1: 1024 blocks
    cvt3_f32_bf16<<<dim3(N4M / 256, 1, 1), 256, 0, stream>>>(
        CVT3{W1, w1_b, W1, w1_b, W1, w1_b}, N4M);
    gemm_bt<EP_BF16_RELU><<<dim3(64, 16), 256, 0, stream>>>(h1, w1_b, nullptr, h2, 2048, 8192, 2048);

    // FFN2: split-K x4 (Kc=2048, 1024 blocks) into 3 partials + d_out; reduce
    cvt3_f32_bf16<<<dim3(N4M / 256, 1, 1), 256, 0, stream>>>(
        CVT3{W2, w2_b, W2, w2_b, W2, w2_b}, N4M);
    gemm_bt_p<<<dim3(16, 16, 4), 256, 0, stream>>>(
        SKP{h2, w2_b, nullptr, FP0, FP1, FP2, (float*)d_out, 2048, 8192, 2048});
    reduce3_into<<<N1M / 256, 256, 0, stream>>>(FP0, FP1, FP2, (float*)d_out, N1M);
}

// Round 6
// 880.736 us; speedup vs baseline: 1.0782x; 1.0782x over previous
//
#include <hip/hip_runtime.h>

typedef unsigned short u16;
typedef __attribute__((ext_vector_type(8))) __bf16 bf16x8;
typedef __attribute__((ext_vector_type(4))) float f32x4;

// ---------- bf16 helpers (OCP bf16 = high 16 bits of fp32, RNE) ----------
__device__ __forceinline__ float b2f(u16 u) {
    unsigned int i = ((unsigned int)u) << 16;
    return __builtin_bit_cast(float, i);
}
__device__ __forceinline__ u16 f2b(float f) {
    unsigned int x = __builtin_bit_cast(unsigned int, f);
    x += 0x7fffu + ((x >> 16) & 1u);
    return (u16)(x >> 16);
}
__device__ __forceinline__ void gld_lds16(const void* g, void* l) {
    __builtin_amdgcn_global_load_lds(
        (const __attribute__((address_space(1))) unsigned int*)g,
        (__attribute__((address_space(3))) unsigned int*)l, 16, 0, 0);
}

// ---------- batched f32 -> bf16 weight conversion (z-fused up to 3) ----------
struct CVT3 { const float* s0; u16* d0; const float* s1; u16* d1;
              const float* s2; u16* d2; };
__global__ __launch_bounds__(256) void cvt3_f32_bf16(CVT3 c, int n4)
{
    const float* s = (blockIdx.z == 0) ? c.s0 : ((blockIdx.z == 1) ? c.s1 : c.s2);
    u16* d = (blockIdx.z == 0) ? c.d0 : ((blockIdx.z == 1) ? c.d1 : c.d2);
    int i = blockIdx.x * 256 + threadIdx.x;
    if (i < n4) {
        float4 v = ((const float4*)s)[i];
        ushort4 o;
        o.x = f2b(v.x); o.y = f2b(v.y); o.z = f2b(v.z); o.w = f2b(v.w);
        ((ushort4*)d)[i] = o;
    }
}

// ---------- reduce 3 partials into io (f32, element-wise) ----------
__global__ __launch_bounds__(256) void reduce3_into(
    const float* __restrict__ p0, const float* __restrict__ p1,
    const float* __restrict__ p2, float* __restrict__ io, int n4)
{
    int i = blockIdx.x * 256 + threadIdx.x;
    if (i < n4) {
        float4 a = ((const float4*)p0)[i];
        float4 b = ((const float4*)p1)[i];
        float4 c = ((const float4*)p2)[i];
        float4 d = ((float4*)io)[i];
        d.x += a.x + b.x + c.x; d.y += a.y + b.y + c.y;
        d.z += a.z + b.z + c.z; d.w += a.w + b.w + c.w;
        ((float4*)io)[i] = d;
    }
}

// ---------- epilogue modes ----------
enum { EP_BF16 = 0, EP_BF16_BIAS, EP_BF16_RELU, EP_BF16_KV, EP_BF16_BIAS_VT, EP_F32_OUT };

// ================= GEMM inner core: 128x128 tile, BK=32, dbuf prefetch =========
// T3-minimum: stage tile t+1 into buf^1 BEFORE computing tile t from buf; single
// __syncthreads() per iter (compiler's implicit vmcnt(0) drains the prefetch
// AFTER compute hid the latency). LDS 2x(8KB A + 8KB B) = 32KB -> occupancy kept.
// T2 rule-#21 swizzle: global_load_lds dest stays linear; the global SOURCE
// 16B-chunk is pre-swizzled (chunk ^ (row&3)) and ds_read applies the same XOR.
// Read bank conflict: 16-way (old 128B rows) -> 4-way.
__device__ __forceinline__ void gemm_core(
    const u16* __restrict__ Ab, const u16* __restrict__ Wb,
    int ldk, int kbeg, int kend, int tid,
    u16 (&As)[2][4096], u16 (&Bs)[2][4096], f32x4 (&acc)[4][4])
{
    const int lane = tid & 63, quad = lane >> 4, l16 = lane & 15;
    const int wave = tid >> 6;
    const int wm = (wave >> 1) * 64, wn = (wave & 1) * 64;
    const int srow = tid >> 2;                       // staging row (r=0 half)
    const int sc = (tid & 3) ^ (srow & 3);           // inverse-swizzled src chunk
    const int xorc = (quad ^ (l16 & 3)) * 16;        // read-side XOR (bytes)

    // loop-invariant staging source pointers (advance by k)
    const u16* pa0 = Ab + (size_t)srow * ldk + kbeg + sc * 8;
    const u16* pa1 = pa0 + (size_t)64 * ldk;
    const u16* pb0 = Wb + (size_t)srow * ldk + kbeg + sc * 8;
    const u16* pb1 = pb0 + (size_t)64 * ldk;
    char* dA = (char*)&As[0][0] + tid * 16;          // buf0 dest; buf1 = +8192
    char* dB = (char*)&Bs[0][0] + tid * 16;

    // prologue: stage tile0 into buf0
    gld_lds16(pa0, dA); gld_lds16(pa1, dA + 4096);
    gld_lds16(pb0, dB); gld_lds16(pb1, dB + 4096);
    __syncthreads();

    int cur = 0;
    const int nk = kend - kbeg;
    for (int ko = 0; ko < nk; ko += 32) {
        if (ko + 32 < nk) {                          // prefetch t+1 into buf^1
            int kn = ko + 32, nb = cur ^ 1;
            gld_lds16(pa0 + kn, dA + nb * 8192);
            gld_lds16(pa1 + kn, dA + nb * 8192 + 4096);
            gld_lds16(pb0 + kn, dB + nb * 8192);
            gld_lds16(pb1 + kn, dB + nb * 8192 + 4096);
        }
        bf16x8 af[4], bfr[4];
#pragma unroll
        for (int i = 0; i < 4; ++i)
            af[i] = *(const bf16x8*)((const char*)&As[cur][0] + (wm + i * 16 + l16) * 64 + xorc);
#pragma unroll
        for (int j = 0; j < 4; ++j)
            bfr[j] = *(const bf16x8*)((const char*)&Bs[cur][0] + (wn + j * 16 + l16) * 64 + xorc);
#pragma unroll
        for (int i = 0; i < 4; ++i)
#pragma unroll
            for (int j = 0; j < 4; ++j)
                acc[i][j] = __builtin_amdgcn_mfma_f32_16x16x32_bf16(af[i], bfr[j], acc[i][j], 0, 0, 0);
        __syncthreads();                             // drains prefetch (vmcnt0) after compute
        cur ^= 1;
    }
}

// C[M,N] = A[M,K] @ W[N,K]^T   (both bf16 row-major, K contiguous)
template <int MODE>
__global__ __launch_bounds__(256) void gemm_bt(
    const u16* __restrict__ A, const u16* __restrict__ W,
    const float* __restrict__ bias, void* __restrict__ out,
    int M, int N, int K)
{
    __shared__ u16 As[2][4096];
    __shared__ u16 Bs[2][4096];
    const int tid = threadIdx.x;
    const int row0 = blockIdx.y * 128, col0 = blockIdx.x * 128;
    const int lane = tid & 63, quad = lane >> 4, l16 = lane & 15;
    const int wave = tid >> 6;
    const int wm = (wave >> 1) * 64, wn = (wave & 1) * 64;

    f32x4 acc[4][4];
#pragma unroll
    for (int i = 0; i < 4; ++i)
#pragma unroll
        for (int j = 0; j < 4; ++j) acc[i][j] = (f32x4){0.f, 0.f, 0.f, 0.f};

    gemm_core(A + (size_t)row0 * K, W + (size_t)col0 * K, K, 0, K, tid, As, Bs, acc);

    // epilogue: C[row=quad*4+reg][col=l16] per 16x16 tile (verified m89/m91 layout)
#pragma unroll
    for (int j = 0; j < 4; ++j) {
        int gcol = col0 + wn + j * 16 + l16;
        float bv = 0.f;
        if (MODE == EP_BF16_BIAS || MODE == EP_BF16_BIAS_VT) bv = bias[gcol];
#pragma unroll
        for (int i = 0; i < 4; ++i) {
            int growb = row0 + wm + i * 16 + quad * 4;
#pragma unroll
            for (int reg = 0; reg < 4; ++reg) {
                int grow = growb + reg;
                float v = acc[i][j][reg] + bv;
                if (MODE == EP_BF16_RELU) v = fmaxf(v, 0.f);
                if (MODE == EP_F32_OUT) {
                    ((float*)out)[(size_t)grow * N + gcol] = v;
                } else if (MODE == EP_BF16_KV) {
                    int b = grow >> 10, s = grow & 1023;
                    ((u16*)out)[((size_t)(b * 1536 + 512 + s)) * N + gcol] = f2b(v);
                } else if (MODE == EP_BF16_BIAS_VT) {
                    int b = (grow >= 1536) ? 1 : 0;
                    int jk = grow - b * 1536;
                    ((u16*)out)[((size_t)(b * 2048 + gcol)) * 1536 + jk] = f2b(v);
                } else {
                    ((u16*)out)[(size_t)grow * N + gcol] = f2b(v);
                }
            }
        }
    }
}

// ---------- z-fused GEMM: blockIdx.z selects an independent (A,W,bias,out,M,mode) ----------
struct FuseA { const u16* A; const u16* W; const float* bias; void* out; int M; int mode; };
struct Fuse3 { FuseA z0, z1, z2; };

__global__ __launch_bounds__(256) void gemm_bt_f(Fuse3 f, int K)
{
    FuseA p = (blockIdx.z == 0) ? f.z0 : ((blockIdx.z == 1) ? f.z1 : f.z2);
    const int row0 = blockIdx.y * 128, col0 = blockIdx.x * 128;
    if (row0 >= p.M) return;   // uniform per block: safe before barriers

    __shared__ u16 As[2][4096];
    __shared__ u16 Bs[2][4096];
    const int tid = threadIdx.x;
    const int lane = tid & 63, quad = lane >> 4, l16 = lane & 15;
    const int wave = tid >> 6;
    const int wm = (wave >> 1) * 64, wn = (wave & 1) * 64;

    f32x4 acc[4][4];
#pragma unroll
    for (int i = 0; i < 4; ++i)
#pragma unroll
        for (int j = 0; j < 4; ++j) acc[i][j] = (f32x4){0.f, 0.f, 0.f, 0.f};

    gemm_core(p.A + (size_t)row0 * K, p.W + (size_t)col0 * K, K, 0, K, tid, As, Bs, acc);

#pragma unroll
    for (int j = 0; j < 4; ++j) {
        int gcol = col0 + wn + j * 16 + l16;
        float bv = (p.mode == EP_BF16_BIAS || p.mode == EP_BF16_BIAS_VT) ? p.bias[gcol] : 0.f;
#pragma unroll
        for (int i = 0; i < 4; ++i) {
            int growb = row0 + wm + i * 16 + quad * 4;
#pragma unroll
            for (int reg = 0; reg < 4; ++reg) {
                int grow = growb + reg;
                u16 hv = f2b(acc[i][j][reg] + bv);
                size_t idx;
                if (p.mode == EP_BF16_KV) {
                    int b = grow >> 10, s = grow & 1023;
                    idx = ((size_t)(b * 1536 + 512 + s)) * 2048 + gcol;
                } else if (p.mode == EP_BF16_BIAS_VT) {
                    int b = (grow >= 1536) ? 1 : 0;
                    int jk = grow - b * 1536;
                    idx = ((size_t)(b * 2048 + gcol)) * 1536 + jk;
                } else {
                    idx = (size_t)grow * 2048 + gcol;
                }
                ((u16*)p.out)[idx] = hv;
            }
        }
    }
}

// ---------- split-K GEMM into per-slice f32 partial buffers (no atomics) ----------
struct SKP { const u16* A; const u16* W; const float* bias;
             float* o0; float* o1; float* o2; float* o3; int N, K, Kc; };

__global__ __launch_bounds__(256) void gemm_bt_p(SKP s)
{
    __shared__ u16 As[2][4096];
    __shared__ u16 Bs[2][4096];
    const int tid = threadIdx.x;
    const int row0 = blockIdx.y * 128, col0 = blockIdx.x * 128;
    const int lane = tid & 63, quad = lane >> 4, l16 = lane & 15;
    const int wave = tid >> 6;
    const int wm = (wave >> 1) * 64, wn = (wave & 1) * 64;
    const int z = blockIdx.z;
    float* out = (z == 0) ? s.o0 : ((z == 1) ? s.o1 : ((z == 2) ? s.o2 : s.o3));
    const int kbeg = z * s.Kc, kend = kbeg + s.Kc;

    f32x4 acc[4][4];
#pragma unroll
    for (int i = 0; i < 4; ++i)
#pragma unroll
        for (int j = 0; j < 4; ++j) acc[i][j] = (f32x4){0.f, 0.f, 0.f, 0.f};

    gemm_core(s.A + (size_t)row0 * s.K, s.W + (size_t)col0 * s.K, s.K,
              kbeg, kend, tid, As, Bs, acc);

#pragma unroll
    for (int j = 0; j < 4; ++j) {
        int gcol = col0 + wn + j * 16 + l16;
        float bv = (s.bias != nullptr && z == 0) ? s.bias[gcol] : 0.f;
#pragma unroll
        for (int i = 0; i < 4; ++i) {
            int growb = row0 + wm + i * 16 + quad * 4;
#pragma unroll
            for (int reg = 0; reg < 4; ++reg) {
                int grow = growb + reg;
                out[(size_t)grow * s.N + gcol] = acc[i][j][reg] + bv;
            }
        }
    }
}

// ---------- LayerNorm over rows of 2048 (input fp32 or bf16, output bf16) ----------
template <int IN_F32>
__global__ __launch_bounds__(256) void ln_rows(
    const void* __restrict__ in, const float* __restrict__ gamma,
    u16* __restrict__ out)
{
    const int row = blockIdx.x, tid = threadIdx.x;
    const float* inf = (const float*)in + (size_t)row * 2048;
    const u16* inb = (const u16*)in + (size_t)row * 2048;
    float v[8], s1 = 0.f, s2 = 0.f;
#pragma unroll
    for (int i = 0; i < 8; ++i) {
        int c = tid + i * 256;
        float x = IN_F32 ? inf[c] : b2f(inb[c]);
        v[i] = x; s1 += x; s2 += x * x;
    }
#pragma unroll
    for (int off = 32; off >= 1; off >>= 1) { s1 += __shfl_xor(s1, off, 64); s2 += __shfl_xor(s2, off, 64); }
    __shared__ float ra[4], rb[4];
    int wave = tid >> 6, lane = tid & 63;
    if (lane == 0) { ra[wave] = s1; rb[wave] = s2; }
    __syncthreads();
    s1 = ra[0] + ra[1] + ra[2] + ra[3];
    s2 = rb[0] + rb[1] + rb[2] + rb[3];
    float mean = s1 * (1.f / 2048.f);
    float var = s2 * (1.f / 2048.f) - mean * mean;
    float rstd = rsqrtf(var + 1e-5f);
#pragma unroll
    for (int i = 0; i < 8; ++i) {
        int c = tid + i * 256;
        out[(size_t)row * 2048 + c] = f2b((v[i] - mean) * rstd * gamma[c]);
    }
}

// ---------- reduce 4 f32 partials + LayerNorm -> bf16 ----------
__global__ __launch_bounds__(256) void ln4_rows(
    const float* __restrict__ p0, const float* __restrict__ p1,
    const float* __restrict__ p2, const float* __restrict__ p3,
    const float* __restrict__ gamma, u16* __restrict__ out)
{
    const int row = blockIdx.x, tid = threadIdx.x;
    const size_t rb_ = (size_t)row * 2048;
    float v[8], s1 = 0.f, s2 = 0.f;
#pragma unroll
    for (int i = 0; i < 8; ++i) {
        int c = tid + i * 256;
        float x = p0[rb_ + c] + p1[rb_ + c] + p2[rb_ + c] + p3[rb_ + c];
        v[i] = x; s1 += x; s2 += x * x;
    }
#pragma unroll
    for (int off = 32; off >= 1; off >>= 1) { s1 += __shfl_xor(s1, off, 64); s2 += __shfl_xor(s2, off, 64); }
    __shared__ float ra[4], rbs[4];
    int wave = tid >> 6, lane = tid & 63;
    if (lane == 0) { ra[wave] = s1; rbs[wave] = s2; }
    __syncthreads();
    s1 = ra[0] + ra[1] + ra[2] + ra[3];
    s2 = rbs[0] + rbs[1] + rbs[2] + rbs[3];
    float mean = s1 * (1.f / 2048.f);
    float rstd = rsqrtf(s2 * (1.f / 2048.f) - mean * mean + 1e-5f);
#pragma unroll
    for (int i = 0; i < 8; ++i) {
        int c = tid + i * 256;
        out[rb_ + c] = f2b((v[i] - mean) * rstd * gamma[c]);
    }
}

// ---------- LN + RoPE for new q,k rows (bf16 pre-activations in ws) ----------
__global__ __launch_bounds__(256) void qk_post(
    const u16* __restrict__ qpre, const u16* __restrict__ kpre,
    const float* __restrict__ gq, const float* __restrict__ gk,
    const float* __restrict__ rotary, const float* __restrict__ xscale,
    u16* __restrict__ qrope, u16* __restrict__ kfull)
{
    const int is_k = blockIdx.x & 1;
    const int row = blockIdx.x >> 1;           // b*1024 + s
    const int b = row >> 10, s = row & 1023;
    const int tid = threadIdx.x, base = tid * 8;
    const u16* in = (is_k ? kpre : qpre) + (size_t)row * 2048;
    float v[8], s1 = 0.f, s2 = 0.f;
#pragma unroll
    for (int i = 0; i < 8; ++i) { float x = b2f(in[base + i]); v[i] = x; s1 += x; s2 += x * x; }
#pragma unroll
    for (int off = 32; off >= 1; off >>= 1) { s1 += __shfl_xor(s1, off, 64); s2 += __shfl_xor(s2, off, 64); }
    __shared__ float ra[4], rb[4];
    int wave = tid >> 6, lane = tid & 63;
    if (lane == 0) { ra[wave] = s1; rb[wave] = s2; }
    __syncthreads();
    s1 = ra[0] + ra[1] + ra[2] + ra[3];
    s2 = rb[0] + rb[1] + rb[2] + rb[3];
    float mean = s1 * (1.f / 2048.f);
    float rstd = rsqrtf(s2 * (1.f / 2048.f) - mean * mean + 1e-5f);
    const float* g = is_k ? gk : gq;
    const int rr = 512 + s;                    // rotary/xscale row
    u16* outp = is_k ? (kfull + ((size_t)(b * 1536 + 512 + s)) * 2048)
                     : (qrope + (size_t)row * 2048);
#pragma unroll
    for (int p = 0; p < 4; ++p) {
        int e0 = base + 2 * p, e1 = e0 + 1;
        float x0 = (v[2 * p] - mean) * rstd * g[e0];
        float x1 = (v[2 * p + 1] - mean) * rstd * g[e1];
        float f = rotary[(size_t)rr * 2048 + e0];
        float sn, cs; sincosf(f, &sn, &cs);
        float sc0 = xscale[(size_t)rr * 2048 + e0];
        float sc1 = xscale[(size_t)rr * 2048 + e1];
        if (is_k) { sc0 = 1.f / sc0; sc1 = 1.f / sc1; }
        outp[e0] = f2b((x0 * cs - x1 * sn) * sc0);
        outp[e1] = f2b((x1 * cs + x0 * sn) * sc1);
    }
}

// ---------- cache rows: rope(cache_k) -> k_full[0..511], cvt cache_v -> v_full ----------
__global__ __launch_bounds__(256) void cache_prep(
    const float* __restrict__ cache_k, const float* __restrict__ cache_v,
    const float* __restrict__ rotary, const float* __restrict__ xscale,
    u16* __restrict__ kfull, u16* __restrict__ vfull)
{
    const int row = blockIdx.x;                // b*512 + j
    const int b = row >> 9, j = row & 511;
    const int base = threadIdx.x * 8;
    const float* ck = cache_k + ((size_t)row) * 2048;
    const float* cv = cache_v + ((size_t)row) * 2048;
    u16* ko = kfull + ((size_t)(b * 1536 + j)) * 2048;
    u16* vo = vfull + ((size_t)(b * 1536 + j)) * 2048;
#pragma unroll
    for (int p = 0; p < 4; ++p) {
        int e0 = base + 2 * p, e1 = e0 + 1;
        float x0 = ck[e0], x1 = ck[e1];
        float f = rotary[(size_t)j * 2048 + e0];
        float sn, cs; sincosf(f, &sn, &cs);
        float sc0 = 1.f / xscale[(size_t)j * 2048 + e0];
        float sc1 = 1.f / xscale[(size_t)j * 2048 + e1];
        ko[e0] = f2b((x0 * cs - x1 * sn) * sc0);
        ko[e1] = f2b((x1 * cs + x0 * sn) * sc1);
        vo[e0] = f2b(cv[e0]); vo[e1] = f2b(cv[e1]);
    }
}

// ---------- banded attention: each query attends to exactly keys (i, i+512] ----------
__global__ __launch_bounds__(256) void attn(
    const u16* __restrict__ qh, const u16* __restrict__ kh,
    const u16* __restrict__ vt, u16* __restrict__ o)
{
    __shared__ u16 Qs[16 * 128];
    __shared__ float Ss[16 * 544];
    __shared__ u16 Ps[16 * 544];
    __shared__ float Ls[16];
    const int qt = blockIdx.x, h = blockIdx.y, b = blockIdx.z;
    const int i0 = qt * 16;
    const int tid = threadIdx.x;
    const int wave = tid >> 6, lane = tid & 63, quad = lane >> 4, l16 = lane & 15;

    { // load 16x128 Q tile (one 16B chunk per thread)
        int r = tid >> 4, seg = tid & 15;
        const u16* src = qh + ((size_t)(b * 1024 + i0 + r)) * 2048 + h * 128 + seg * 8;
        *(uint4*)(Qs + r * 128 + seg * 8) = *(const uint4*)src;
    }
    __syncthreads();

    const float sm = 0.08838834764831845f;  // 1/sqrt(128)
    for (int kt = wave; kt < 33; kt += 4) {
        int jb = i0 + kt * 16;
        const u16* krow = kh + ((size_t)(b * 1536 + jb + l16)) * 2048 + h * 128 + quad * 8;
        const u16* qrow = Qs + l16 * 128 + quad * 8;
        f32x4 sacc = (f32x4){0.f, 0.f, 0.f, 0.f};
#pragma unroll
        for (int st = 0; st < 4; ++st) {
            bf16x8 aq = *(const bf16x8*)(qrow + st * 32);
            bf16x8 bk = *(const bf16x8*)(krow + st * 32);
            sacc = __builtin_amdgcn_mfma_f32_16x16x32_bf16(aq, bk, sacc, 0, 0, 0);
        }
        int jj = jb + l16;
#pragma unroll
        for (int reg = 0; reg < 4; ++reg) {
            int qi = i0 + quad * 4 + reg;
            bool valid = (jj > qi) && (jj <= qi + 512);
            Ss[(quad * 4 + reg) * 544 + kt * 16 + l16] = valid ? sacc[reg] * sm : -1e9f;
        }
    }
    __syncthreads();

    { // softmax: 16 threads per query row
        int g = tid >> 4, l = tid & 15;
        float m = -1e30f;
        for (int j = l; j < 528; j += 16) m = fmaxf(m, Ss[g * 544 + j]);
#pragma unroll
        for (int off = 8; off >= 1; off >>= 1) m = fmaxf(m, __shfl_xor(m, off, 16));
        float sum = 0.f;
        for (int j = l; j < 528; j += 16) {
            float e = __expf(Ss[g * 544 + j] - m);
            sum += e;
            Ps[g * 544 + j] = f2b(e);
        }
        Ps[g * 544 + 528 + l] = 0;   // pad keys 528..543
#pragma unroll
        for (int off = 8; off >= 1; off >>= 1) sum += __shfl_xor(sum, off, 16);
        if (l == 0) Ls[g] = sum;
    }
    __syncthreads();

    // O = P @ V via MFMA; V read transposed (contiguous in key)
    f32x4 oa0 = (f32x4){0.f, 0.f, 0.f, 0.f}, oa1 = oa0;
    const u16* vbase = vt + ((size_t)(b * 2048 + h * 128 + wave * 32 + l16)) * 1536 + i0;
    for (int jc = 0; jc < 17; ++jc) {
        bf16x8 pf = *(const bf16x8*)(Ps + l16 * 544 + jc * 32 + quad * 8);
        bf16x8 v0 = *(const bf16x8*)(vbase + jc * 32 + quad * 8);
        bf16x8 v1 = *(const bf16x8*)(vbase + (size_t)16 * 1536 + jc * 32 + quad * 8);
        oa0 = __builtin_amdgcn_mfma_f32_16x16x32_bf16(pf, v0, oa0, 0, 0, 0);
        oa1 = __builtin_amdgcn_mfma_f32_16x16x32_bf16(pf, v1, oa1, 0, 0, 0);
    }
#pragma unroll
    for (int reg = 0; reg < 4; ++reg) {
        int q = quad * 4 + reg;
        float inv = 1.f / Ls[q];
        size_t orow = ((size_t)(b * 1024 + i0 + q)) * 2048 + h * 128 + wave * 32;
        o[orow + l16] = f2b(oa0[reg] * inv);
        o[orow + 16 + l16] = f2b(oa1[reg] * inv);
    }
}

// ---------- launch ----------
extern "C" void kernel_launch(void* const* d_in, const int* in_sizes, int n_in,
                              void* d_out, int out_size, void* d_ws, size_t ws_size,
                              hipStream_t stream)
{
    const float* x       = (const float*)d_in[0];
    const float* cache_k = (const float*)d_in[1];
    const float* cache_v = (const float*)d_in[2];
    const float* rotary  = (const float*)d_in[3];
    const float* xscale  = (const float*)d_in[4];
    // d_in[5] mask: band computed analytically
    const float* g_in = (const float*)d_in[6];
    const float* Wq   = (const float*)d_in[7];
    const float* Wk   = (const float*)d_in[8];
    const float* Wv   = (const float*)d_in[9];
    const float* g_q  = (const float*)d_in[10];
    const float* g_k  = (const float*)d_in[11];
    const float* Wlq  = (const float*)d_in[12];
    const float* blq  = (const float*)d_in[13];
    const float* Wlk  = (const float*)d_in[14];
    const float* blk  = (const float*)d_in[15];
    const float* Wlv  = (const float*)d_in[16];
    const float* blv  = (const float*)d_in[17];
    const float* Wo   = (const float*)d_in[18];
    const float* bo   = (const float*)d_in[19];
    const float* g_ffn= (const float*)d_in[20];
    const float* W1   = (const float*)d_in[21];
    const float* W2   = (const float*)d_in[22];

    char* ws = (char*)d_ws;
    // slot map (bytes) — time-multiplexed, high-water 117.5MB (validated):
    u16* xn     = (u16*)(ws + 0);
    u16* qpre   = (u16*)(ws + 8388608);
    u16* kpre   = (u16*)(ws + 16777216);
    u16* wq_b   = (u16*)(ws + 25165824);
    u16* khb    = (u16*)(ws + 25165824);
    u16* vfull  = (u16*)(ws + 37748736);
    u16* wv_b   = (u16*)(ws + 50331648);
    u16* kfull  = (u16*)(ws + 50331648);
    u16* wk_b   = (u16*)(ws + 62914560);
    u16* vt     = (u16*)(ws + 62914560);
    u16* qrope  = (u16*)(ws + 75563008);
    u16* wlq_b  = (u16*)(ws + 83951616);
    u16* wlk_b  = (u16*)(ws + 92340224);
    u16* wlv_b  = (u16*)(ws + 100728832);
    u16* h2     = (u16*)(ws + 83951616);
    u16* qhb    = qpre;
    u16* obuf   = xn;
    u16* h1     = qrope;                      // over dead qrope
    u16* wo_b   = (u16*)(ws + 25165824);
    u16* w1_b   = (u16*)(ws + 0);             // 33.55MB [0,33.55)
    u16* w2_b   = (u16*)(ws + 0);
    // Wo partials (4 x 16.78MB f32), live Wo-GEMM..ln4:
    float* WP0  = (float*)(ws + 33554432);
    float* WP1  = (float*)(ws + 50331648);
    float* WP2  = (float*)(ws + 83951616);
    float* WP3  = (float*)(ws + 8388608);
    // FFN2 partials (3 x 16.78MB f32 + d_out), live FFN2..reduce:
    float* FP0  = (float*)(ws + 33554432);
    float* FP1  = (float*)(ws + 50331648);
    float* FP2  = (float*)(ws + 67108864);

    const int N1M = 4194304 / 4;    // 2048*2048 /4 (float4 count)
    const int N4M = 16777216 / 4;   // 8192*2048 /4

    ln_rows<1><<<2048, 256, 0, stream>>>(x, g_in, xn);
    cvt3_f32_bf16<<<dim3(N1M / 256, 1, 3), 256, 0, stream>>>(
        CVT3{Wq, wq_b, Wk, wk_b, Wv, wv_b}, N1M);

    // fused QKV: 768 blocks (3/CU)
    Fuse3 fq;
    fq.z0 = FuseA{xn, wq_b, nullptr, (void*)qpre,  2048, EP_BF16};
    fq.z1 = FuseA{xn, wk_b, nullptr, (void*)kpre,  2048, EP_BF16};
    fq.z2 = FuseA{xn, wv_b, nullptr, (void*)vfull, 2048, EP_BF16_KV};
    gemm_bt_f<<<dim3(16, 16, 3), 256, 0, stream>>>(fq, 2048);

    cache_prep<<<1024, 256, 0, stream>>>(cache_k, cache_v, rotary, xscale, kfull, vfull);
    qk_post<<<4096, 256, 0, stream>>>(qpre, kpre, g_q, g_k, rotary, xscale, qrope, kfull);
    cvt3_f32_bf16<<<dim3(N1M / 256, 1, 3), 256, 0, stream>>>(
        CVT3{Wlq, wlq_b, Wlk, wlk_b, Wlv, wlv_b}, N1M);

    // fused linear projections: 1152 blocks (1024 active, 4/CU)
    Fuse3 fl;
    fl.z0 = FuseA{qrope, wlq_b, blq, (void*)qhb, 2048, EP_BF16_BIAS};
    fl.z1 = FuseA{kfull, wlk_b, blk, (void*)khb, 3072, EP_BF16_BIAS};
    fl.z2 = FuseA{vfull, wlv_b, blv, (void*)vt,  3072, EP_BF16_BIAS_VT};
    gemm_bt_f<<<dim3(16, 24, 3), 256, 0, stream>>>(fl, 2048);

    attn<<<dim3(64, 16, 2), 256, 0, stream>>>(qhb, khb, vt, obuf);

    // Wo: split-K x4 (Kc=512, 1024 blocks) into f32 partials, no atomics
    cvt3_f32_bf16<<<dim3(N1M / 256, 1, 1), 256, 0, stream>>>(
        CVT3{Wo, wo_b, Wo, wo_b, Wo, wo_b}, N1M);
    gemm_bt_p<<<dim3(16, 16, 4), 256, 0, stream>>>(
        SKP{obuf, wo_b, bo, WP0, WP1, WP2, WP3, 2048, 2048, 512});
    ln4_rows<<<2048, 256, 0, stream>>>(WP0, WP1, WP2, WP3, g_ffn, h1);

    // FFN1: 1024 blocks (4/CU)
    cvt3_f32_bf16<<<dim3(N4M / 256, 1, 1), 256, 0, stream>>>(
        CVT3{W1, w1_b, W1, w1_b, W1, w1_b}, N4M);
    gemm_bt<EP_BF16_RELU><<<dim3(64, 16), 256, 0, stream>>>(h1, w1_b, nullptr, h2, 2048, 8192, 2048);

    // FFN2: split-K x4 (Kc=2048, 1024 blocks) into 3 partials + d_out; reduce
    cvt3_f32_bf16<<<dim3(N4M / 256, 1, 1), 256, 0, stream>>>(
        CVT3{W2, w2_b, W2, w2_b, W2, w2_b}, N4M);
    gemm_bt_p<<<dim3(16, 16, 4), 256, 0, stream>>>(
        SKP{h2, w2_b, nullptr, FP0, FP1, FP2, (float*)d_out, 2048, 8192, 2048});
    reduce3_into<<<N1M / 256, 256, 0, stream>>>(FP0, FP1, FP2, (float*)d_out, N1M);
}